// Round 1
// baseline (1002.433 us; speedup 1.0000x reference)
//
#include <hip/hip_runtime.h>

#define H 512
#define E2d 512
#define NTOK 64
#define NPIX 49
#define CDIM 2048
#define VOCAB 10000

// ws layout (float offsets)
#define WS_S      0         // 64x512
#define WS_G2     32768     // 64x512
#define WS_A0     65536     // 64x2048 (cxt then alpha0 in place)
#define WS_FM     196608    // 8x2048
#define WS_HWG    212992    // 64x64 (49 used)
#define WS_CS     217088    // 64x64 (49 used)
#define WS_M      221184    // 64 x MSTRIDE_N
#define MSTRIDE_N 2560
#define MSTRIDE_K2 52
#define WS_CCHAN  385024    // 64x64
#define WS_CSPAT  389120    // 64x2048
#define WS_SPAT   520192    // 64x512 (atomic accum)
#define WS_SGATE  552960    // 64x512
#define WS_CGATE  585728    // 64x512
#define WS_CHAT   618496    // 64x512

#define OUT_ALPHA 640000
#define OUT_BETA  643136

__device__ __forceinline__ float rcp_fast(float x) {
#if __has_builtin(__builtin_amdgcn_rcpf)
  return __builtin_amdgcn_rcpf(x);
#else
  return 1.0f / x;
#endif
}
__device__ __forceinline__ float tanh_f(float x) {
  float e = __expf(2.0f * x);           // inf for large x -> rcp(inf)=0 -> 1
  return 1.0f - 2.0f * rcp_fast(e + 1.0f);
}
__device__ __forceinline__ float sigmoid_f(float x) {
  return rcp_fast(1.0f + __expf(-x));
}

__global__ void k_zero(float* p, int n) {
  int i = blockIdx.x * 256 + threadIdx.x;
  if (i < n) p[i] = 0.0f;
}

__global__ void k_featmean(const float* __restrict__ V, float* __restrict__ ws) {
  int b = blockIdx.y;
  int c = blockIdx.x * 256 + threadIdx.x;
  float s = 0.0f;
  for (int k = 0; k < NPIX; ++k) s += V[b * NPIX * CDIM + k * CDIM + c];
  ws[WS_FM + b * CDIM + c] = s * (1.0f / NPIX);
}

// s = sigmoid(x@Wsx + hprev@Wsh) * tanh(cells)   [lane=token GEMM, Nc=4, grid 32]
__global__ __launch_bounds__(256) void k_s(const float* __restrict__ x,
    const float* __restrict__ hid, const float* __restrict__ cells,
    const float* __restrict__ Wsx, const float* __restrict__ Wsh,
    float* __restrict__ ws) {
  __shared__ float xT[64 * 65], hT[64 * 65];
  int tid = threadIdx.x, lane = tid & 63, w = tid >> 6;
  int cbase = __builtin_amdgcn_readfirstlane(blockIdx.x * 16 + w * 4);
  float acc[4] = {0.f, 0.f, 0.f, 0.f};
  for (int kc = 0; kc < 8; ++kc) {
    __syncthreads();
    for (int i = 0; i < 16; ++i) {
      int idx = i * 256 + tid, tok = idx >> 6, kk = idx & 63;
      int gk = kc * 64 + kk;
      xT[kk * 65 + tok] = x[tok * E2d + gk];
      hT[kk * 65 + tok] = (tok & 7) ? hid[(tok - 1) * H + gk] : 0.0f;
    }
    __syncthreads();
#pragma unroll 4
    for (int kk = 0; kk < 64; ++kk) {
      float a1 = xT[kk * 65 + lane];
      float a2 = hT[kk * 65 + lane];
      int gk = kc * 64 + kk;
#pragma unroll
      for (int j = 0; j < 4; ++j)
        acc[j] += a1 * Wsx[gk * H + cbase + j] + a2 * Wsh[gk * H + cbase + j];
    }
  }
#pragma unroll
  for (int j = 0; j < 4; ++j) {
    int c = cbase + j;
    ws[WS_S + lane * H + c] = sigmoid_f(acc[j]) * tanh_f(cells[lane * H + c]);
  }
}

// g2 = h @ Wg2   [Nc=8, grid 16]
__global__ __launch_bounds__(256) void k_g2(const float* __restrict__ hid,
    const float* __restrict__ Wg2, float* __restrict__ ws) {
  __shared__ float aT[64 * 65];
  int tid = threadIdx.x, lane = tid & 63, w = tid >> 6;
  int cbase = __builtin_amdgcn_readfirstlane(blockIdx.x * 32 + w * 8);
  float acc[8] = {0.f,0.f,0.f,0.f,0.f,0.f,0.f,0.f};
  for (int kc = 0; kc < 8; ++kc) {
    __syncthreads();
    for (int i = 0; i < 16; ++i) {
      int idx = i * 256 + tid, tok = idx >> 6, kk = idx & 63;
      aT[kk * 65 + tok] = hid[tok * H + kc * 64 + kk];
    }
    __syncthreads();
#pragma unroll 4
    for (int kk = 0; kk < 64; ++kk) {
      float a = aT[kk * 65 + lane];
      int gk = kc * 64 + kk;
#pragma unroll
      for (int j = 0; j < 8; ++j) acc[j] += a * Wg2[gk * H + cbase + j];
    }
  }
#pragma unroll
  for (int j = 0; j < 8; ++j) ws[WS_G2 + lane * H + cbase + j] = acc[j];
}

// cxt[n][c] = sum_j tanh(fm[b][c]*Wfeat[j] + g2[n][j]) * Wcxt[j]
__global__ __launch_bounds__(256) void k_cxt(const float* __restrict__ Wfeat,
    const float* __restrict__ Wcxt, float* __restrict__ ws) {
  __shared__ float2 fw[512];
  __shared__ float g2l[512];
  int tid = threadIdx.x, n = blockIdx.y, b = n >> 3;
  int c = blockIdx.x * 256 + tid;
  for (int i = tid; i < 512; i += 256) {
    fw[i] = make_float2(Wfeat[i], Wcxt[i]);
    g2l[i] = ws[WS_G2 + n * H + i];
  }
  __syncthreads();
  float fm = ws[WS_FM + b * CDIM + c];
  float acc = 0.0f;
#pragma unroll 4
  for (int j = 0; j < 512; ++j) {
    float2 p = fw[j];
    acc += tanh_f(fm * p.x + g2l[j]) * p.y;
  }
  ws[WS_A0 + n * CDIM + c] = acc;
}

// softmax over 2048, in place on WS_A0
__global__ __launch_bounds__(256) void k_softmax0(float* __restrict__ ws) {
  __shared__ float red[4];
  int n = blockIdx.x, tid = threadIdx.x, lane = tid & 63, w = tid >> 6;
  float* row = ws + WS_A0 + n * CDIM;
  float v[8];
  float m = -1e30f;
#pragma unroll
  for (int i = 0; i < 8; ++i) { v[i] = row[tid + i * 256]; m = fmaxf(m, v[i]); }
  for (int off = 32; off; off >>= 1) m = fmaxf(m, __shfl_xor(m, off));
  if (lane == 0) red[w] = m;
  __syncthreads();
  m = fmaxf(fmaxf(red[0], red[1]), fmaxf(red[2], red[3]));
  float s = 0.0f;
#pragma unroll
  for (int i = 0; i < 8; ++i) { v[i] = __expf(v[i] - m); s += v[i]; }
  for (int off = 32; off; off >>= 1) s += __shfl_xor(s, off);
  __syncthreads();
  if (lane == 0) red[w] = s;
  __syncthreads();
  s = red[0] + red[1] + red[2] + red[3];
  float inv = rcp_fast(s);
#pragma unroll
  for (int i = 0; i < 8; ++i) row[tid + i * 256] = v[i] * inv;
}

// hWg = h@Wg ; content_s = s@Ws + h@Wg   (per token block)
__global__ __launch_bounds__(256) void k_cs_hwg(const float* __restrict__ hid,
    const float* __restrict__ Wg, const float* __restrict__ Ws_,
    float* __restrict__ ws) {
  __shared__ float sl[512], hl[512];
  __shared__ float r1[4][64], r2[4][64];
  int tid = threadIdx.x, n = blockIdx.x;
  for (int i = tid; i < 512; i += 256) {
    sl[i] = ws[WS_S + n * H + i];
    hl[i] = hid[n * H + i];
  }
  __syncthreads();
  int k2 = tid & 63, seg = tid >> 6;
  float a1 = 0.0f, a2 = 0.0f;
  if (k2 < NPIX) {
    for (int e = seg * 128; e < seg * 128 + 128; ++e) {
      a1 += hl[e] * Wg[e * NPIX + k2];
      a2 += sl[e] * Ws_[e * NPIX + k2];
    }
  }
  r1[seg][k2] = a1; r2[seg][k2] = a2;
  __syncthreads();
  if (seg == 0 && k2 < NPIX) {
    float h1 = r1[0][k2] + r1[1][k2] + r1[2][k2] + r1[3][k2];
    float s2 = r2[0][k2] + r2[1][k2] + r2[2][k2] + r2[3][k2];
    ws[WS_HWG + n * 64 + k2] = h1;
    ws[WS_CS + n * 64 + k2] = h1 + s2;
  }
}

// c_channel[n][k] = mean_c alpha0[n][c]*V[b][k][c]
__global__ __launch_bounds__(64) void k_cchan(const float* __restrict__ V,
    float* __restrict__ ws) {
  int k = blockIdx.x, n = blockIdx.y, b = n >> 3, lane = threadIdx.x;
  const float* a0 = ws + WS_A0 + n * CDIM;
  const float* vr = V + b * NPIX * CDIM + k * CDIM;
  float s = 0.0f;
  for (int c = lane; c < CDIM; c += 64) s += a0[c] * vr[c];
  for (int off = 32; off; off >>= 1) s += __shfl_xor(s, off);
  if (lane == 0) ws[WS_CCHAN + n * 64 + k] = s * (1.0f / CDIM);
}

// M[n][k2][k] += sum_c (alpha0*V)[k][c] * Wv[c][k2]   (c-split x16, atomic accum)
__global__ __launch_bounds__(256) void k_attnM(const float* __restrict__ V,
    const float* __restrict__ Wv, float* __restrict__ ws) {
  __shared__ float u[128 * 53 + 16];
  int tid = threadIdx.x, n = blockIdx.y, b = n >> 3;
  int c0 = blockIdx.x * 128;
  const float* a0 = ws + WS_A0 + n * CDIM;
  for (int i = 0; i < 25; ++i) {
    int idx = i * 256 + tid;
    if (idx < NPIX * 128) {
      int k = idx >> 7, cc = idx & 127;
      u[cc * 53 + k] = a0[c0 + cc] * V[b * NPIX * CDIM + k * CDIM + c0 + cc];
    }
  }
  __syncthreads();
  int lane = tid & 63, w = tid >> 6;
  int k2base = __builtin_amdgcn_readfirstlane(w * 13);
  int nk2 = (w < 3) ? 13 : 10;
  float acc[13];
#pragma unroll
  for (int j = 0; j < 13; ++j) acc[j] = 0.0f;
#pragma unroll 2
  for (int cc = 0; cc < 128; ++cc) {
    float uv = u[cc * 53 + lane];
    const float* wrow = Wv + (c0 + cc) * NPIX;
#pragma unroll
    for (int j = 0; j < 13; ++j) {
      int k2 = k2base + j; if (k2 > 48) k2 = 48;
      acc[j] += uv * wrow[k2];
    }
  }
  if (lane < NPIX) {
    for (int j = 0; j < nk2; ++j)
      atomicAdd(&ws[WS_M + n * MSTRIDE_N + (k2base + j) * MSTRIDE_K2 + lane], acc[j]);
  }
}

// z_t, alpha_t (out), z_ext, beta (out)
__global__ __launch_bounds__(64) void k_zt(const float* __restrict__ Wh,
    float* __restrict__ ws, float* __restrict__ out) {
  __shared__ float gl[NPIX], whl[NPIX];
  int n = blockIdx.x, lane = threadIdx.x;
  if (lane < NPIX) {
    gl[lane] = ws[WS_HWG + n * 64 + lane];
    whl[lane] = Wh[lane];
  }
  __syncthreads();
  float z = 0.0f;
  if (lane < NPIX) {
    for (int k2 = 0; k2 < NPIX; ++k2) {
      float m = ws[WS_M + n * MSTRIDE_N + k2 * MSTRIDE_K2 + lane];
      z += tanh_f(tanh_f(m + gl[k2])) * whl[k2];
    }
  }
  float zm = (lane < NPIX) ? z : -1e30f;
  float m1 = zm;
  for (int off = 32; off; off >>= 1) m1 = fmaxf(m1, __shfl_xor(m1, off));
  float e = (lane < NPIX) ? __expf(z - m1) : 0.0f;
  float S1 = e;
  for (int off = 32; off; off >>= 1) S1 += __shfl_xor(S1, off);
  if (lane < NPIX) out[OUT_ALPHA + n * NPIX + lane] = e * rcp_fast(S1);
  float vz = (lane < NPIX) ? tanh_f(ws[WS_CS + n * 64 + lane]) * whl[lane] : 0.0f;
  for (int off = 32; off; off >>= 1) vz += __shfl_xor(vz, off);
  if (lane == 0) {
    float ze = vz;
    float m2 = fmaxf(m1, ze);
    float S2 = S1 * __expf(m1 - m2) + __expf(ze - m2);
    out[OUT_BETA + n] = __expf(ze - m2) * rcp_fast(S2);
  }
}

// c_spatial[n][d] = sum_k alpha_t[n][k] * V[b][k][d]
__global__ __launch_bounds__(256) void k_cspatial(const float* __restrict__ V,
    const float* __restrict__ out, float* __restrict__ ws) {
  __shared__ float al[NPIX];
  int tid = threadIdx.x, n = blockIdx.y, b = n >> 3;
  int d = blockIdx.x * 256 + tid;
  if (tid < NPIX) al[tid] = out[OUT_ALPHA + n * NPIX + tid];
  __syncthreads();
  float s = 0.0f;
#pragma unroll 7
  for (int k = 0; k < NPIX; ++k) s += al[k] * V[b * NPIX * CDIM + k * CDIM + d];
  ws[WS_CSPAT + n * CDIM + d] = s;
}

// spatial_info = c_spatial @ Wspat  (K=2048 split x4, atomic accum)
__global__ __launch_bounds__(256) void k_spat(const float* __restrict__ Wspat,
    float* __restrict__ ws) {
  __shared__ float aT[128 * 65];
  int tid = threadIdx.x, lane = tid & 63, w = tid >> 6;
  int cbase = __builtin_amdgcn_readfirstlane(blockIdx.x * 32 + w * 8);
  int kb = blockIdx.y * 512;
  float acc[8] = {0.f,0.f,0.f,0.f,0.f,0.f,0.f,0.f};
  for (int kc = 0; kc < 4; ++kc) {
    __syncthreads();
    for (int i = 0; i < 32; ++i) {
      int idx = i * 256 + tid, tok = idx >> 7, kk = idx & 127;
      aT[kk * 65 + tok] = ws[WS_CSPAT + tok * CDIM + kb + kc * 128 + kk];
    }
    __syncthreads();
#pragma unroll 4
    for (int kk = 0; kk < 128; ++kk) {
      float a = aT[kk * 65 + lane];
      int gk = kb + kc * 128 + kk;
#pragma unroll
      for (int j = 0; j < 8; ++j) acc[j] += a * Wspat[gk * H + cbase + j];
    }
  }
#pragma unroll
  for (int j = 0; j < 8; ++j)
    atomicAdd(&ws[WS_SPAT + lane * H + cbase + j], acc[j]);
}

// s_gate = sigmoid(s@Wgvs + h@Wghs); c_gate = sigmoid(s@Wgvc + h@Wghc)
__global__ __launch_bounds__(256) void k_gates(const float* __restrict__ hid,
    const float* __restrict__ Wgvs, const float* __restrict__ Wgvc,
    const float* __restrict__ Wghs, const float* __restrict__ Wghc,
    float* __restrict__ ws) {
  __shared__ float sT[64 * 65], hT[64 * 65];
  int tid = threadIdx.x, lane = tid & 63, w = tid >> 6;
  int cbase = __builtin_amdgcn_readfirstlane(blockIdx.x * 8 + w * 2);
  float as[2] = {0.f, 0.f}, ac[2] = {0.f, 0.f};
  for (int kc = 0; kc < 8; ++kc) {
    __syncthreads();
    for (int i = 0; i < 16; ++i) {
      int idx = i * 256 + tid, tok = idx >> 6, kk = idx & 63;
      sT[kk * 65 + tok] = ws[WS_S + tok * H + kc * 64 + kk];
      hT[kk * 65 + tok] = hid[tok * H + kc * 64 + kk];
    }
    __syncthreads();
#pragma unroll 4
    for (int kk = 0; kk < 64; ++kk) {
      float a1 = sT[kk * 65 + lane], a2 = hT[kk * 65 + lane];
      int gk = kc * 64 + kk;
#pragma unroll
      for (int j = 0; j < 2; ++j) {
        as[j] += a1 * Wgvs[gk * H + cbase + j] + a2 * Wghs[gk * H + cbase + j];
        ac[j] += a1 * Wgvc[gk * H + cbase + j] + a2 * Wghc[gk * H + cbase + j];
      }
    }
  }
#pragma unroll
  for (int j = 0; j < 2; ++j) {
    ws[WS_SGATE + lane * H + cbase + j] = sigmoid_f(as[j]);
    ws[WS_CGATE + lane * H + cbase + j] = sigmoid_f(ac[j]);
  }
}

// chat = s_gate*spatial + c_gate*(c_channel@Wchan) + h
__global__ __launch_bounds__(256) void k_chat(const float* __restrict__ hid,
    const float* __restrict__ Wchan, float* __restrict__ ws) {
  __shared__ float cl[NPIX];
  int tid = threadIdx.x, n = blockIdx.y;
  int c = blockIdx.x * 256 + tid;
  if (tid < NPIX) cl[tid] = ws[WS_CCHAN + n * 64 + tid];
  __syncthreads();
  float acc = 0.0f;
#pragma unroll 7
  for (int k = 0; k < NPIX; ++k) acc += cl[k] * Wchan[k * H + c];
  float chat = ws[WS_SGATE + n * H + c] * ws[WS_SPAT + n * H + c]
             + ws[WS_CGATE + n * H + c] * acc + hid[n * H + c];
  ws[WS_CHAT + n * H + c] = chat;
}

// scores = (chat) @ Wmlp + bmlp
__global__ __launch_bounds__(256) void k_scores(const float* __restrict__ Wmlp,
    const float* __restrict__ bmlp, float* __restrict__ ws,
    float* __restrict__ out) {
  __shared__ float aT[128 * 65];
  int tid = threadIdx.x, lane = tid & 63, w = tid >> 6;
  int cbase = __builtin_amdgcn_readfirstlane(blockIdx.x * 32 + w * 8);
  float acc[8] = {0.f,0.f,0.f,0.f,0.f,0.f,0.f,0.f};
  for (int kc = 0; kc < 4; ++kc) {
    __syncthreads();
    for (int i = 0; i < 32; ++i) {
      int idx = i * 256 + tid, tok = idx >> 7, kk = idx & 127;
      aT[kk * 65 + tok] = ws[WS_CHAT + tok * H + kc * 128 + kk];
    }
    __syncthreads();
#pragma unroll 4
    for (int kk = 0; kk < 128; ++kk) {
      float a = aT[kk * 65 + lane];
      int gk = kc * 128 + kk;
#pragma unroll
      for (int j = 0; j < 8; ++j) {
        int c = cbase + j; if (c > VOCAB - 1) c = VOCAB - 1;
        acc[j] += a * Wmlp[gk * VOCAB + c];
      }
    }
  }
#pragma unroll
  for (int j = 0; j < 8; ++j) {
    int c = cbase + j;
    if (c < VOCAB) out[lane * VOCAB + c] = acc[j] + bmlp[c];
  }
}

extern "C" void kernel_launch(void* const* d_in, const int* in_sizes, int n_in,
                              void* d_out, int out_size, void* d_ws, size_t ws_size,
                              hipStream_t stream) {
  const float* x     = (const float*)d_in[0];
  const float* hid   = (const float*)d_in[1];
  const float* cells = (const float*)d_in[2];
  const float* V     = (const float*)d_in[3];
  const float* Wsx   = (const float*)d_in[4];
  const float* Wsh   = (const float*)d_in[5];
  const float* Wv    = (const float*)d_in[6];
  const float* Wg    = (const float*)d_in[7];
  const float* Ws_   = (const float*)d_in[8];
  const float* Wh    = (const float*)d_in[9];
  const float* Wfeat = (const float*)d_in[10];
  const float* Wcxt  = (const float*)d_in[11];
  const float* Wg2   = (const float*)d_in[12];
  const float* Wspat = (const float*)d_in[13];
  const float* Wchan = (const float*)d_in[14];
  const float* Wgvs  = (const float*)d_in[15];
  const float* Wgvc  = (const float*)d_in[16];
  const float* Wghs  = (const float*)d_in[17];
  const float* Wghc  = (const float*)d_in[18];
  const float* Wmlp  = (const float*)d_in[19];
  const float* bmlp  = (const float*)d_in[20];
  float* ws  = (float*)d_ws;
  float* out = (float*)d_out;

  hipLaunchKernelGGL(k_zero, dim3(640), dim3(256), 0, stream, ws + WS_M, 64 * MSTRIDE_N);
  hipLaunchKernelGGL(k_zero, dim3(128), dim3(256), 0, stream, ws + WS_SPAT, NTOK * H);
  hipLaunchKernelGGL(k_featmean, dim3(8, 8), dim3(256), 0, stream, V, ws);
  hipLaunchKernelGGL(k_s, dim3(32), dim3(256), 0, stream, x, hid, cells, Wsx, Wsh, ws);
  hipLaunchKernelGGL(k_g2, dim3(16), dim3(256), 0, stream, hid, Wg2, ws);
  hipLaunchKernelGGL(k_cxt, dim3(8, 64), dim3(256), 0, stream, Wfeat, Wcxt, ws);
  hipLaunchKernelGGL(k_softmax0, dim3(64), dim3(256), 0, stream, ws);
  hipLaunchKernelGGL(k_cs_hwg, dim3(64), dim3(256), 0, stream, hid, Wg, Ws_, ws);
  hipLaunchKernelGGL(k_cchan, dim3(49, 64), dim3(64), 0, stream, V, ws);
  hipLaunchKernelGGL(k_attnM, dim3(16, 64), dim3(256), 0, stream, V, Wv, ws);
  hipLaunchKernelGGL(k_zt, dim3(64), dim3(64), 0, stream, Wh, ws, out);
  hipLaunchKernelGGL(k_cspatial, dim3(8, 64), dim3(256), 0, stream, V, out, ws);
  hipLaunchKernelGGL(k_spat, dim3(16, 4), dim3(256), 0, stream, Wspat, ws);
  hipLaunchKernelGGL(k_gates, dim3(64), dim3(256), 0, stream, hid, Wgvs, Wgvc, Wghs, Wghc, ws);
  hipLaunchKernelGGL(k_chat, dim3(2, 64), dim3(256), 0, stream, hid, Wchan, ws);
  hipLaunchKernelGGL(k_scores, dim3(313), dim3(256), 0, stream, Wmlp, bmlp, ws, out);
}

// Round 2
// 425.966 us; speedup vs baseline: 2.3533x; 2.3533x over previous
//
#include <hip/hip_runtime.h>

#define H 512
#define E2d 512
#define NTOK 64
#define NPIX 49
#define CDIM 2048
#define VOCAB 10000

// ws layout (float offsets)
#define WS_S      0         // 64x512
#define WS_G2     32768     // 64x512
#define WS_A0     65536     // 64x2048 (cxt then alpha0 in place; later reused as SPATP)
#define WS_SPATP  65536     // 4x64x512 K-split partials of spatial_info (aliases A0, dead by then)
#define WS_FM     196608    // 8x2048
#define WS_HWG    212992    // 64x64 (49 used)
#define WS_CS     217088    // 64x64 (49 used)
#define WS_M      221184    // 64 x MSTRIDE_N
#define MSTRIDE_N 2560
#define MSTRIDE_K2 52
#define WS_CCHAN  385024    // 64x64
#define WS_CSPAT  389120    // 64x2048
#define WS_SGATE  520192    // 64x512
#define WS_CGATE  552960    // 64x512
#define WS_CHAT   585728    // 64x512

#define OUT_ALPHA 640000
#define OUT_BETA  643136

__device__ __forceinline__ float rcp_fast(float x) {
#if __has_builtin(__builtin_amdgcn_rcpf)
  return __builtin_amdgcn_rcpf(x);
#else
  return 1.0f / x;
#endif
}
__device__ __forceinline__ float tanh_f(float x) {
  float e = __expf(2.0f * x);           // inf for large x -> rcp(inf)=0 -> 1
  return 1.0f - 2.0f * rcp_fast(e + 1.0f);
}
__device__ __forceinline__ float sigmoid_f(float x) {
  return rcp_fast(1.0f + __expf(-x));
}

__global__ void k_zero(float* p, int n) {
  int i = blockIdx.x * 256 + threadIdx.x;
  if (i < n) p[i] = 0.0f;
}

__global__ void k_featmean(const float* __restrict__ V, float* __restrict__ ws) {
  int b = blockIdx.y;
  int c = blockIdx.x * 256 + threadIdx.x;
  float s = 0.0f;
  for (int k = 0; k < NPIX; ++k) s += V[b * NPIX * CDIM + k * CDIM + c];
  ws[WS_FM + b * CDIM + c] = s * (1.0f / NPIX);
}

// s = sigmoid(x@Wsx + hprev@Wsh) * tanh(cells)
// one block per token; lanes span c (float4 coalesced weight loads); 2-way K-split in-block
__global__ __launch_bounds__(256) void k_s(const float* __restrict__ x,
    const float* __restrict__ hid, const float* __restrict__ cells,
    const float* __restrict__ Wsx, const float* __restrict__ Wsh,
    float* __restrict__ ws) {
  __shared__ float xs[512], hs[512];
  __shared__ float4 pbuf[128];
  int tid = threadIdx.x, n = blockIdx.x;
  for (int i = tid; i < 512; i += 256) {
    xs[i] = x[n * E2d + i];
    hs[i] = (n & 7) ? hid[(n - 1) * H + i] : 0.0f;
  }
  __syncthreads();
  int c4 = tid & 127, kh = tid >> 7;
  const float4* Wx4 = (const float4*)Wsx;
  const float4* Wh4 = (const float4*)Wsh;
  float4 acc = {0.f, 0.f, 0.f, 0.f};
  int k0 = kh * 256;
#pragma unroll 4
  for (int kk = 0; kk < 256; ++kk) {
    int k = k0 + kk;
    float ax = xs[k], ah = hs[k];
    float4 wx = Wx4[k * 128 + c4];
    float4 wh = Wh4[k * 128 + c4];
    acc.x += ax * wx.x + ah * wh.x;
    acc.y += ax * wx.y + ah * wh.y;
    acc.z += ax * wx.z + ah * wh.z;
    acc.w += ax * wx.w + ah * wh.w;
  }
  if (kh == 1) pbuf[c4] = acc;
  __syncthreads();
  if (kh == 0) {
    float4 p = pbuf[c4];
    acc.x += p.x; acc.y += p.y; acc.z += p.z; acc.w += p.w;
    float4 cl = ((const float4*)(cells + n * H))[c4];
    float4 o;
    o.x = sigmoid_f(acc.x) * tanh_f(cl.x);
    o.y = sigmoid_f(acc.y) * tanh_f(cl.y);
    o.z = sigmoid_f(acc.z) * tanh_f(cl.z);
    o.w = sigmoid_f(acc.w) * tanh_f(cl.w);
    ((float4*)(ws + WS_S + n * H))[c4] = o;
  }
}

// g2 = h @ Wg2
__global__ __launch_bounds__(256) void k_g2(const float* __restrict__ hid,
    const float* __restrict__ Wg2, float* __restrict__ ws) {
  __shared__ float hs[512];
  __shared__ float4 pbuf[128];
  int tid = threadIdx.x, n = blockIdx.x;
  for (int i = tid; i < 512; i += 256) hs[i] = hid[n * H + i];
  __syncthreads();
  int c4 = tid & 127, kh = tid >> 7;
  const float4* W4 = (const float4*)Wg2;
  float4 acc = {0.f, 0.f, 0.f, 0.f};
  int k0 = kh * 256;
#pragma unroll 4
  for (int kk = 0; kk < 256; ++kk) {
    int k = k0 + kk;
    float a = hs[k];
    float4 w = W4[k * 128 + c4];
    acc.x += a * w.x; acc.y += a * w.y; acc.z += a * w.z; acc.w += a * w.w;
  }
  if (kh == 1) pbuf[c4] = acc;
  __syncthreads();
  if (kh == 0) {
    float4 p = pbuf[c4];
    acc.x += p.x; acc.y += p.y; acc.z += p.z; acc.w += p.w;
    ((float4*)(ws + WS_G2 + n * H))[c4] = acc;
  }
}

// cxt[n][c] = sum_j tanh(fm[b][c]*Wfeat[j] + g2[n][j]) * Wcxt[j]
__global__ __launch_bounds__(256) void k_cxt(const float* __restrict__ Wfeat,
    const float* __restrict__ Wcxt, float* __restrict__ ws) {
  __shared__ float2 fw[512];
  __shared__ float g2l[512];
  int tid = threadIdx.x, n = blockIdx.y, b = n >> 3;
  int c = blockIdx.x * 256 + tid;
  for (int i = tid; i < 512; i += 256) {
    fw[i] = make_float2(Wfeat[i], Wcxt[i]);
    g2l[i] = ws[WS_G2 + n * H + i];
  }
  __syncthreads();
  float fm = ws[WS_FM + b * CDIM + c];
  float acc = 0.0f;
#pragma unroll 4
  for (int j = 0; j < 512; ++j) {
    float2 p = fw[j];
    acc += tanh_f(fm * p.x + g2l[j]) * p.y;
  }
  ws[WS_A0 + n * CDIM + c] = acc;
}

// softmax over 2048, in place on WS_A0
__global__ __launch_bounds__(256) void k_softmax0(float* __restrict__ ws) {
  __shared__ float red[4];
  int n = blockIdx.x, tid = threadIdx.x, lane = tid & 63, w = tid >> 6;
  float* row = ws + WS_A0 + n * CDIM;
  float v[8];
  float m = -1e30f;
#pragma unroll
  for (int i = 0; i < 8; ++i) { v[i] = row[tid + i * 256]; m = fmaxf(m, v[i]); }
  for (int off = 32; off; off >>= 1) m = fmaxf(m, __shfl_xor(m, off));
  if (lane == 0) red[w] = m;
  __syncthreads();
  m = fmaxf(fmaxf(red[0], red[1]), fmaxf(red[2], red[3]));
  float s = 0.0f;
#pragma unroll
  for (int i = 0; i < 8; ++i) { v[i] = __expf(v[i] - m); s += v[i]; }
  for (int off = 32; off; off >>= 1) s += __shfl_xor(s, off);
  __syncthreads();
  if (lane == 0) red[w] = s;
  __syncthreads();
  s = red[0] + red[1] + red[2] + red[3];
  float inv = rcp_fast(s);
#pragma unroll
  for (int i = 0; i < 8; ++i) row[tid + i * 256] = v[i] * inv;
}

// hWg = h@Wg ; content_s = s@Ws + h@Wg   (per token block)
__global__ __launch_bounds__(256) void k_cs_hwg(const float* __restrict__ hid,
    const float* __restrict__ Wg, const float* __restrict__ Ws_,
    float* __restrict__ ws) {
  __shared__ float sl[512], hl[512];
  __shared__ float r1[4][64], r2[4][64];
  int tid = threadIdx.x, n = blockIdx.x;
  for (int i = tid; i < 512; i += 256) {
    sl[i] = ws[WS_S + n * H + i];
    hl[i] = hid[n * H + i];
  }
  __syncthreads();
  int k2 = tid & 63, seg = tid >> 6;
  float a1 = 0.0f, a2 = 0.0f;
  if (k2 < NPIX) {
    for (int e = seg * 128; e < seg * 128 + 128; ++e) {
      a1 += hl[e] * Wg[e * NPIX + k2];
      a2 += sl[e] * Ws_[e * NPIX + k2];
    }
  }
  r1[seg][k2] = a1; r2[seg][k2] = a2;
  __syncthreads();
  if (seg == 0 && k2 < NPIX) {
    float h1 = r1[0][k2] + r1[1][k2] + r1[2][k2] + r1[3][k2];
    float s2 = r2[0][k2] + r2[1][k2] + r2[2][k2] + r2[3][k2];
    ws[WS_HWG + n * 64 + k2] = h1;
    ws[WS_CS + n * 64 + k2] = h1 + s2;
  }
}

// c_channel[n][k] = mean_c alpha0[n][c]*V[b][k][c]
__global__ __launch_bounds__(64) void k_cchan(const float* __restrict__ V,
    float* __restrict__ ws) {
  int k = blockIdx.x, n = blockIdx.y, b = n >> 3, lane = threadIdx.x;
  const float* a0 = ws + WS_A0 + n * CDIM;
  const float* vr = V + b * NPIX * CDIM + k * CDIM;
  float s = 0.0f;
  for (int c = lane; c < CDIM; c += 64) s += a0[c] * vr[c];
  for (int off = 32; off; off >>= 1) s += __shfl_xor(s, off);
  if (lane == 0) ws[WS_CCHAN + n * 64 + k] = s * (1.0f / CDIM);
}

// M[n][k2][k] += sum_c (alpha0*V)[k][c] * Wv[c][k2]   (c-split x16, atomic accum)
__global__ __launch_bounds__(256) void k_attnM(const float* __restrict__ V,
    const float* __restrict__ Wv, float* __restrict__ ws) {
  __shared__ float u[128 * 53 + 16];
  int tid = threadIdx.x, n = blockIdx.y, b = n >> 3;
  int c0 = blockIdx.x * 128;
  const float* a0 = ws + WS_A0 + n * CDIM;
  for (int i = 0; i < 25; ++i) {
    int idx = i * 256 + tid;
    if (idx < NPIX * 128) {
      int k = idx >> 7, cc = idx & 127;
      u[cc * 53 + k] = a0[c0 + cc] * V[b * NPIX * CDIM + k * CDIM + c0 + cc];
    }
  }
  __syncthreads();
  int lane = tid & 63, w = tid >> 6;
  int k2base = __builtin_amdgcn_readfirstlane(w * 13);
  int nk2 = (w < 3) ? 13 : 10;
  float acc[13];
#pragma unroll
  for (int j = 0; j < 13; ++j) acc[j] = 0.0f;
#pragma unroll 2
  for (int cc = 0; cc < 128; ++cc) {
    float uv = u[cc * 53 + lane];
    const float* wrow = Wv + (c0 + cc) * NPIX;
#pragma unroll
    for (int j = 0; j < 13; ++j) {
      int k2 = k2base + j; if (k2 > 48) k2 = 48;
      acc[j] += uv * wrow[k2];
    }
  }
  if (lane < NPIX) {
    for (int j = 0; j < nk2; ++j)
      atomicAdd(&ws[WS_M + n * MSTRIDE_N + (k2base + j) * MSTRIDE_K2 + lane], acc[j]);
  }
}

// z_t, alpha_t (out), z_ext, beta (out)
__global__ __launch_bounds__(64) void k_zt(const float* __restrict__ Wh,
    float* __restrict__ ws, float* __restrict__ out) {
  __shared__ float gl[NPIX], whl[NPIX];
  int n = blockIdx.x, lane = threadIdx.x;
  if (lane < NPIX) {
    gl[lane] = ws[WS_HWG + n * 64 + lane];
    whl[lane] = Wh[lane];
  }
  __syncthreads();
  float z = 0.0f;
  if (lane < NPIX) {
    for (int k2 = 0; k2 < NPIX; ++k2) {
      float m = ws[WS_M + n * MSTRIDE_N + k2 * MSTRIDE_K2 + lane];
      z += tanh_f(tanh_f(m + gl[k2])) * whl[k2];
    }
  }
  float zm = (lane < NPIX) ? z : -1e30f;
  float m1 = zm;
  for (int off = 32; off; off >>= 1) m1 = fmaxf(m1, __shfl_xor(m1, off));
  float e = (lane < NPIX) ? __expf(z - m1) : 0.0f;
  float S1 = e;
  for (int off = 32; off; off >>= 1) S1 += __shfl_xor(S1, off);
  if (lane < NPIX) out[OUT_ALPHA + n * NPIX + lane] = e * rcp_fast(S1);
  float vz = (lane < NPIX) ? tanh_f(ws[WS_CS + n * 64 + lane]) * whl[lane] : 0.0f;
  for (int off = 32; off; off >>= 1) vz += __shfl_xor(vz, off);
  if (lane == 0) {
    float ze = vz;
    float m2 = fmaxf(m1, ze);
    float S2 = S1 * __expf(m1 - m2) + __expf(ze - m2);
    out[OUT_BETA + n] = __expf(ze - m2) * rcp_fast(S2);
  }
}

// c_spatial[n][d] = sum_k alpha_t[n][k] * V[b][k][d]
__global__ __launch_bounds__(256) void k_cspatial(const float* __restrict__ V,
    const float* __restrict__ out, float* __restrict__ ws) {
  __shared__ float al[NPIX];
  int tid = threadIdx.x, n = blockIdx.y, b = n >> 3;
  int d = blockIdx.x * 256 + tid;
  if (tid < NPIX) al[tid] = out[OUT_ALPHA + n * NPIX + tid];
  __syncthreads();
  float s = 0.0f;
#pragma unroll 7
  for (int k = 0; k < NPIX; ++k) s += al[k] * V[b * NPIX * CDIM + k * CDIM + d];
  ws[WS_CSPAT + n * CDIM + d] = s;
}

// spatial_info partials: grid (n, kq); each block does K-quarter (512 of 2048)
// writes partial to WS_SPATP[kq][n][c]; k_chat sums the 4 partials
__global__ __launch_bounds__(256) void k_spat(const float* __restrict__ Wspat,
    float* __restrict__ ws) {
  __shared__ float as[512];
  __shared__ float4 pbuf[128];
  int tid = threadIdx.x, n = blockIdx.x, kq = blockIdx.y;
  for (int i = tid; i < 512; i += 256)
    as[i] = ws[WS_CSPAT + n * CDIM + kq * 512 + i];
  __syncthreads();
  int c4 = tid & 127, kh = tid >> 7;
  const float4* W4 = (const float4*)Wspat;
  float4 acc = {0.f, 0.f, 0.f, 0.f};
  int k0 = kh * 256;
#pragma unroll 4
  for (int kk = 0; kk < 256; ++kk) {
    int k = k0 + kk;
    float a = as[k];
    float4 w = W4[(kq * 512 + k) * 128 + c4];
    acc.x += a * w.x; acc.y += a * w.y; acc.z += a * w.z; acc.w += a * w.w;
  }
  if (kh == 1) pbuf[c4] = acc;
  __syncthreads();
  if (kh == 0) {
    float4 p = pbuf[c4];
    acc.x += p.x; acc.y += p.y; acc.z += p.z; acc.w += p.w;
    ((float4*)(ws + WS_SPATP + kq * 32768 + n * H))[c4] = acc;
  }
}

// gates: grid (n, gy); gy=0 -> s_gate(Wgvs,Wghs), gy=1 -> c_gate(Wgvc,Wghc)
__global__ __launch_bounds__(256) void k_gates(const float* __restrict__ hid,
    const float* __restrict__ Wgvs, const float* __restrict__ Wgvc,
    const float* __restrict__ Wghs, const float* __restrict__ Wghc,
    float* __restrict__ ws) {
  __shared__ float sl[512], hl[512];
  __shared__ float4 pbuf[128];
  int tid = threadIdx.x, n = blockIdx.x, gy = blockIdx.y;
  for (int i = tid; i < 512; i += 256) {
    sl[i] = ws[WS_S + n * H + i];
    hl[i] = hid[n * H + i];
  }
  __syncthreads();
  const float4* Wv4 = (const float4*)(gy ? Wgvc : Wgvs);
  const float4* Wh4 = (const float4*)(gy ? Wghc : Wghs);
  int c4 = tid & 127, kh = tid >> 7;
  float4 acc = {0.f, 0.f, 0.f, 0.f};
  int k0 = kh * 256;
#pragma unroll 4
  for (int kk = 0; kk < 256; ++kk) {
    int k = k0 + kk;
    float a1 = sl[k], a2 = hl[k];
    float4 wv = Wv4[k * 128 + c4];
    float4 wh = Wh4[k * 128 + c4];
    acc.x += a1 * wv.x + a2 * wh.x;
    acc.y += a1 * wv.y + a2 * wh.y;
    acc.z += a1 * wv.z + a2 * wh.z;
    acc.w += a1 * wv.w + a2 * wh.w;
  }
  if (kh == 1) pbuf[c4] = acc;
  __syncthreads();
  if (kh == 0) {
    float4 p = pbuf[c4];
    float4 o;
    o.x = sigmoid_f(acc.x + p.x);
    o.y = sigmoid_f(acc.y + p.y);
    o.z = sigmoid_f(acc.z + p.z);
    o.w = sigmoid_f(acc.w + p.w);
    ((float4*)(ws + (gy ? WS_CGATE : WS_SGATE) + n * H))[c4] = o;
  }
}

// chat = s_gate*spatial(sum of 4 partials) + c_gate*(c_channel@Wchan) + h
__global__ __launch_bounds__(256) void k_chat(const float* __restrict__ hid,
    const float* __restrict__ Wchan, float* __restrict__ ws) {
  __shared__ float cl[NPIX];
  int tid = threadIdx.x, n = blockIdx.y;
  int c = blockIdx.x * 256 + tid;
  if (tid < NPIX) cl[tid] = ws[WS_CCHAN + n * 64 + tid];
  __syncthreads();
  float acc = 0.0f;
#pragma unroll 7
  for (int k = 0; k < NPIX; ++k) acc += cl[k] * Wchan[k * H + c];
  float spat = ws[WS_SPATP + 0 * 32768 + n * H + c]
             + ws[WS_SPATP + 1 * 32768 + n * H + c]
             + ws[WS_SPATP + 2 * 32768 + n * H + c]
             + ws[WS_SPATP + 3 * 32768 + n * H + c];
  float chat = ws[WS_SGATE + n * H + c] * spat
             + ws[WS_CGATE + n * H + c] * acc + hid[n * H + c];
  ws[WS_CHAT + n * H + c] = chat;
}

// scores = chat @ Wmlp + bmlp; grid (n fast, c-chunk of 512); float2 loads
__global__ __launch_bounds__(256) void k_scores(const float* __restrict__ Wmlp,
    const float* __restrict__ bmlp, float* __restrict__ ws,
    float* __restrict__ out) {
  __shared__ float ch[512];
  int tid = threadIdx.x, n = blockIdx.x, cy = blockIdx.y;
  for (int i = tid; i < 512; i += 256) ch[i] = ws[WS_CHAT + n * H + i];
  __syncthreads();
  int c0 = cy * 512 + tid * 2;
  if (c0 >= VOCAB) return;
  const float2* W2 = (const float2*)Wmlp;
  int cw = c0 >> 1;
  float2 acc = {0.f, 0.f};
#pragma unroll 8
  for (int k = 0; k < 512; ++k) {
    float a = ch[k];
    float2 w = W2[k * (VOCAB / 2) + cw];
    acc.x += a * w.x;
    acc.y += a * w.y;
  }
  float2 b2 = ((const float2*)bmlp)[cw];
  acc.x += b2.x;
  acc.y += b2.y;
  ((float2*)(out + n * VOCAB))[cw] = acc;
}

extern "C" void kernel_launch(void* const* d_in, const int* in_sizes, int n_in,
                              void* d_out, int out_size, void* d_ws, size_t ws_size,
                              hipStream_t stream) {
  const float* x     = (const float*)d_in[0];
  const float* hid   = (const float*)d_in[1];
  const float* cells = (const float*)d_in[2];
  const float* V     = (const float*)d_in[3];
  const float* Wsx   = (const float*)d_in[4];
  const float* Wsh   = (const float*)d_in[5];
  const float* Wv    = (const float*)d_in[6];
  const float* Wg    = (const float*)d_in[7];
  const float* Ws_   = (const float*)d_in[8];
  const float* Wh    = (const float*)d_in[9];
  const float* Wfeat = (const float*)d_in[10];
  const float* Wcxt  = (const float*)d_in[11];
  const float* Wg2   = (const float*)d_in[12];
  const float* Wspat = (const float*)d_in[13];
  const float* Wchan = (const float*)d_in[14];
  const float* Wgvs  = (const float*)d_in[15];
  const float* Wgvc  = (const float*)d_in[16];
  const float* Wghs  = (const float*)d_in[17];
  const float* Wghc  = (const float*)d_in[18];
  const float* Wmlp  = (const float*)d_in[19];
  const float* bmlp  = (const float*)d_in[20];
  float* ws  = (float*)d_ws;
  float* out = (float*)d_out;

  hipLaunchKernelGGL(k_zero, dim3(640), dim3(256), 0, stream, ws + WS_M, 64 * MSTRIDE_N);
  hipLaunchKernelGGL(k_featmean, dim3(8, 8), dim3(256), 0, stream, V, ws);
  hipLaunchKernelGGL(k_s, dim3(64), dim3(256), 0, stream, x, hid, cells, Wsx, Wsh, ws);
  hipLaunchKernelGGL(k_g2, dim3(64), dim3(256), 0, stream, hid, Wg2, ws);
  hipLaunchKernelGGL(k_cxt, dim3(8, 64), dim3(256), 0, stream, Wfeat, Wcxt, ws);
  hipLaunchKernelGGL(k_softmax0, dim3(64), dim3(256), 0, stream, ws);
  hipLaunchKernelGGL(k_cs_hwg, dim3(64), dim3(256), 0, stream, hid, Wg, Ws_, ws);
  hipLaunchKernelGGL(k_cchan, dim3(49, 64), dim3(64), 0, stream, V, ws);
  hipLaunchKernelGGL(k_attnM, dim3(16, 64), dim3(256), 0, stream, V, Wv, ws);
  hipLaunchKernelGGL(k_zt, dim3(64), dim3(64), 0, stream, Wh, ws, out);
  hipLaunchKernelGGL(k_cspatial, dim3(8, 64), dim3(256), 0, stream, V, out, ws);
  hipLaunchKernelGGL(k_spat, dim3(64, 4), dim3(256), 0, stream, Wspat, ws);
  hipLaunchKernelGGL(k_gates, dim3(64, 2), dim3(256), 0, stream, hid, Wgvs, Wgvc, Wghs, Wghc, ws);
  hipLaunchKernelGGL(k_chat, dim3(2, 64), dim3(256), 0, stream, hid, Wchan, ws);
  hipLaunchKernelGGL(k_scores, dim3(64, 20), dim3(256), 0, stream, Wmlp, bmlp, ws, out);
}

// Round 3
// 380.166 us; speedup vs baseline: 2.6368x; 1.1205x over previous
//
#include <hip/hip_runtime.h>

#define H 512
#define E2d 512
#define NTOK 64
#define NPIX 49
#define CDIM 2048
#define VOCAB 10000

// ws layout (float offsets). Zero region first (one k_zero launch).
#define WS_M      0         // 64 tok x (49 k2 x 49 k) stride-packed
#define MSTRIDE_N 2432      // 49*49=2401 padded
#define MSTRIDE_K2 49
#define WS_SACC   155648    // 64x512 acc: x@Wsx + hprev@Wsh
#define WS_G2     188416    // 64x512 acc: h@Wg2 (identity)
#define WS_GA1    221184    // 64x512 acc: s@Wgvs + h@Wghs
#define WS_GA2    253952    // 64x512 acc: s@Wgvc + h@Wghc
#define WS_SPAT   286720    // 64x512 acc: c_spatial@Wspat (identity)
#define WS_CCHAN  319488    // 64x64 acc (49 used)
#define ZERO_N    323584

#define WS_S      323584    // 64x512 row-major s
#define WS_ST     356352    // 512x64 s transposed
#define WS_HT     389120    // 512x64 h transposed
#define WS_A0     421888    // 64x2048 cxt/alpha0; later CSPT; later CHT
#define WS_CSPT   421888    // 2048x64 c_spatial^T (alias A0, dead after attnM)
#define WS_CHT    421888    // 512x64 chat^T (alias, dead after spat gemm)
#define WS_XT     552960    // 512x64 x^T; later SG
#define WS_SG     552960    // 64x512 s_gate (alias XT, dead after s gemm)
#define WS_HPT    585728    // 512x64 hprev^T; later CG
#define WS_CG     585728    // 64x512 c_gate (alias HPT)
#define WS_FM     618496    // 8x2048 featmean
#define WS_HWG    634880    // 64x64 (49 used)
#define WS_CS     638976    // 64x64 (49 used)
// end 643072 floats

#define OUT_ALPHA 640000
#define OUT_BETA  643136

__device__ __forceinline__ float rcp_fast(float x) {
#if __has_builtin(__builtin_amdgcn_rcpf)
  return __builtin_amdgcn_rcpf(x);
#else
  return 1.0f / x;
#endif
}
__device__ __forceinline__ float tanh_f(float x) {
  float e = __expf(2.0f * x);           // inf for large x -> rcp(inf)=0 -> 1
  return 1.0f - 2.0f * rcp_fast(e + 1.0f);
}
__device__ __forceinline__ float sigmoid_f(float x) {
  return rcp_fast(1.0f + __expf(-x));
}

__global__ void k_zero(float* __restrict__ p, int n) {
  int i = blockIdx.x * 256 + threadIdx.x;
  if (i < n) p[i] = 0.0f;
}

// out[n][c] = bmlp[c]
__global__ void k_bias(const float* __restrict__ bmlp, float* __restrict__ out) {
  int c = blockIdx.x * 256 + threadIdx.x, n = blockIdx.y;
  if (c < VOCAB) out[n * VOCAB + c] = bmlp[c];
}

__global__ void k_featmean(const float* __restrict__ V, float* __restrict__ ws) {
  int b = blockIdx.y;
  int c = blockIdx.x * 256 + threadIdx.x;
  float s = 0.0f;
  for (int k = 0; k < NPIX; ++k) s += V[b * NPIX * CDIM + k * CDIM + c];
  ws[WS_FM + b * CDIM + c] = s * (1.0f / NPIX);
}

// transposes: by 0: x -> XT, 1: hid -> HT, 2: hprev -> HPT   (all [512][64])
__global__ void k_tr(const float* __restrict__ x, const float* __restrict__ hid,
                     float* __restrict__ ws) {
  int by = blockIdx.y;
  int idx = blockIdx.x * 256 + threadIdx.x;   // 0..32767
  int n = idx >> 9, k = idx & 511;
  float v;
  float* dst;
  if (by == 0)      { v = x[idx];                                dst = ws + WS_XT; }
  else if (by == 1) { v = hid[idx];                              dst = ws + WS_HT; }
  else              { v = (n & 7) ? hid[idx - 512] : 0.0f;       dst = ws + WS_HPT; }
  dst[k * 64 + n] = v;
}

// ---- multi-token skinny GEMM core: C[64][N] += A^T[K][64] (chunk) @ W[K][N] ----
// per thread: one output column c, all 64 tokens in registers.
// A loads are wave-uniform (scalarize to s_load); W loads coalesced; atomic combine.
__device__ __forceinline__ void gemm_body(const float* __restrict__ A,
    const float* __restrict__ W, float* __restrict__ C,
    int k0, int nk, int c, int N) {
  const float4* __restrict__ A4 = (const float4*)A;
  float acc[64];
#pragma unroll
  for (int n = 0; n < 64; ++n) acc[n] = 0.f;
#pragma unroll 2
  for (int kk = 0; kk < nk; ++kk) {
    int k = k0 + kk;
    float w = W[k * N + c];
#pragma unroll
    for (int n4 = 0; n4 < 16; ++n4) {
      float4 a = A4[k * 16 + n4];
      acc[n4 * 4 + 0] += a.x * w;
      acc[n4 * 4 + 1] += a.y * w;
      acc[n4 * 4 + 2] += a.z * w;
      acc[n4 * 4 + 3] += a.w * w;
    }
  }
#pragma unroll
  for (int n = 0; n < 64; ++n) atomicAdd(&C[n * N + c], acc[n]);
}

// SACC += x@Wsx + hprev@Wsh ; grid (2, 32)
__global__ __launch_bounds__(256) void k_gemm_s(const float* __restrict__ Wsx,
    const float* __restrict__ Wsh, float* __restrict__ ws) {
  int c = blockIdx.x * 256 + threadIdx.x;
  int kc = blockIdx.y;
  const float* A = (kc < 16) ? ws + WS_XT : ws + WS_HPT;
  const float* W = (kc < 16) ? Wsx : Wsh;
  gemm_body(A, W, ws + WS_SACC, (kc & 15) * 32, 32, c, 512);
}

// G2 += h@Wg2 ; grid (2, 16)
__global__ __launch_bounds__(256) void k_gemm_g2(const float* __restrict__ Wg2,
    float* __restrict__ ws) {
  int c = blockIdx.x * 256 + threadIdx.x;
  int kc = blockIdx.y;
  gemm_body(ws + WS_HT, Wg2, ws + WS_G2, kc * 32, 32, c, 512);
}

// GA1 += s@Wgvs + h@Wghs ; GA2 += s@Wgvc + h@Wghc ; grid (2, 32, 2)
__global__ __launch_bounds__(256) void k_gemm_gates(const float* __restrict__ Wgvs,
    const float* __restrict__ Wghs, const float* __restrict__ Wgvc,
    const float* __restrict__ Wghc, float* __restrict__ ws) {
  int c = blockIdx.x * 256 + threadIdx.x;
  int kc = blockIdx.y, z = blockIdx.z;
  const float* A = (kc < 16) ? ws + WS_ST : ws + WS_HT;
  const float* W = z ? ((kc < 16) ? Wgvc : Wghc) : ((kc < 16) ? Wgvs : Wghs);
  float* C = ws + (z ? WS_GA2 : WS_GA1);
  gemm_body(A, W, C, (kc & 15) * 32, 32, c, 512);
}

// SPAT += c_spatial@Wspat ; grid (2, 64), K=2048
__global__ __launch_bounds__(256) void k_gemm_spat(const float* __restrict__ Wspat,
    float* __restrict__ ws) {
  int c = blockIdx.x * 256 + threadIdx.x;
  int kc = blockIdx.y;
  gemm_body(ws + WS_CSPT, Wspat, ws + WS_SPAT, kc * 32, 32, c, 512);
}

// out += chat@Wmlp ; grid (40, 8), kchunk 64
__global__ __launch_bounds__(256) void k_gemm_scores(const float* __restrict__ Wmlp,
    float* __restrict__ ws, float* __restrict__ out) {
  int c = blockIdx.x * 256 + threadIdx.x;
  if (c >= VOCAB) return;
  int kc = blockIdx.y;
  gemm_body(ws + WS_CHT, Wmlp, out, kc * 64, 64, c, VOCAB);
}

// s = sigmoid(SACC)*tanh(cells) -> S (row-major) and ST (transposed)
__global__ void k_act_s(const float* __restrict__ cells, float* __restrict__ ws) {
  int idx = blockIdx.x * 256 + threadIdx.x;   // 0..32767
  int n = idx >> 9, c = idx & 511;
  float v = sigmoid_f(ws[WS_SACC + idx]) * tanh_f(cells[idx]);
  ws[WS_S + idx] = v;
  ws[WS_ST + c * 64 + n] = v;
}

// gates: SG = sigmoid(GA1), CG = sigmoid(GA2)
__global__ void k_act_g(float* __restrict__ ws) {
  int idx = blockIdx.x * 256 + threadIdx.x;
  ws[WS_SG + idx] = sigmoid_f(ws[WS_GA1 + idx]);
  ws[WS_CG + idx] = sigmoid_f(ws[WS_GA2 + idx]);
}

// cxt[n][c] = sum_j tanh(fm[b][c]*Wfeat[j] + g2[n][j]) * Wcxt[j]
__global__ __launch_bounds__(256) void k_cxt(const float* __restrict__ Wfeat,
    const float* __restrict__ Wcxt, float* __restrict__ ws) {
  __shared__ float2 fw[512];
  __shared__ float g2l[512];
  int tid = threadIdx.x, n = blockIdx.y, b = n >> 3;
  int c = blockIdx.x * 256 + tid;
  for (int i = tid; i < 512; i += 256) {
    fw[i] = make_float2(Wfeat[i], Wcxt[i]);
    g2l[i] = ws[WS_G2 + n * H + i];
  }
  __syncthreads();
  float fm = ws[WS_FM + b * CDIM + c];
  float acc = 0.0f;
#pragma unroll 4
  for (int j = 0; j < 512; ++j) {
    float2 p = fw[j];
    acc += tanh_f(fm * p.x + g2l[j]) * p.y;
  }
  ws[WS_A0 + n * CDIM + c] = acc;
}

// softmax over 2048, in place on WS_A0
__global__ __launch_bounds__(256) void k_softmax0(float* __restrict__ ws) {
  __shared__ float red[4];
  int n = blockIdx.x, tid = threadIdx.x, lane = tid & 63, w = tid >> 6;
  float* row = ws + WS_A0 + n * CDIM;
  float v[8];
  float m = -1e30f;
#pragma unroll
  for (int i = 0; i < 8; ++i) { v[i] = row[tid + i * 256]; m = fmaxf(m, v[i]); }
  for (int off = 32; off; off >>= 1) m = fmaxf(m, __shfl_xor(m, off));
  if (lane == 0) red[w] = m;
  __syncthreads();
  m = fmaxf(fmaxf(red[0], red[1]), fmaxf(red[2], red[3]));
  float s = 0.0f;
#pragma unroll
  for (int i = 0; i < 8; ++i) { v[i] = __expf(v[i] - m); s += v[i]; }
  for (int off = 32; off; off >>= 1) s += __shfl_xor(s, off);
  __syncthreads();
  if (lane == 0) red[w] = s;
  __syncthreads();
  s = red[0] + red[1] + red[2] + red[3];
  float inv = rcp_fast(s);
#pragma unroll
  for (int i = 0; i < 8; ++i) row[tid + i * 256] = v[i] * inv;
}

// hWg = h@Wg ; content_s = s@Ws + h@Wg   (per token block)
__global__ __launch_bounds__(256) void k_cs_hwg(const float* __restrict__ hid,
    const float* __restrict__ Wg, const float* __restrict__ Ws_,
    float* __restrict__ ws) {
  __shared__ float sl[512], hl[512];
  __shared__ float r1[4][64], r2[4][64];
  int tid = threadIdx.x, n = blockIdx.x;
  for (int i = tid; i < 512; i += 256) {
    sl[i] = ws[WS_S + n * H + i];
    hl[i] = hid[n * H + i];
  }
  __syncthreads();
  int k2 = tid & 63, seg = tid >> 6;
  float a1 = 0.0f, a2 = 0.0f;
  if (k2 < NPIX) {
    for (int e = seg * 128; e < seg * 128 + 128; ++e) {
      a1 += hl[e] * Wg[e * NPIX + k2];
      a2 += sl[e] * Ws_[e * NPIX + k2];
    }
  }
  r1[seg][k2] = a1; r2[seg][k2] = a2;
  __syncthreads();
  if (seg == 0 && k2 < NPIX) {
    float h1 = r1[0][k2] + r1[1][k2] + r1[2][k2] + r1[3][k2];
    float s2 = r2[0][k2] + r2[1][k2] + r2[2][k2] + r2[3][k2];
    ws[WS_HWG + n * 64 + k2] = h1;
    ws[WS_CS + n * 64 + k2] = h1 + s2;
  }
}

// M[n][k2][k] += sum_c (alpha0*V)[k][c]*Wv[c][k2]  + fused c_channel partials
__global__ __launch_bounds__(256) void k_attnM(const float* __restrict__ V,
    const float* __restrict__ Wv, float* __restrict__ ws) {
  __shared__ float u[128 * 53 + 16];
  __shared__ float red2[4][52];
  int tid = threadIdx.x, n = blockIdx.y, b = n >> 3;
  int c0 = blockIdx.x * 128;
  const float* a0 = ws + WS_A0 + n * CDIM;
  for (int i = 0; i < 25; ++i) {
    int idx = i * 256 + tid;
    if (idx < NPIX * 128) {
      int k = idx >> 7, cc = idx & 127;
      u[cc * 53 + k] = a0[c0 + cc] * V[b * NPIX * CDIM + k * CDIM + c0 + cc];
    }
  }
  __syncthreads();
  // fused c_channel partial: cchan[n][k] += (1/CDIM) * sum_cc u[cc][k]
  if (tid < 196) {
    int k = tid >> 2, q = tid & 3;
    float p = 0.0f;
    for (int cc = q * 32; cc < q * 32 + 32; ++cc) p += u[cc * 53 + k];
    red2[q][k] = p;
  }
  __syncthreads();
  if (tid < NPIX) {
    float t = red2[0][tid] + red2[1][tid] + red2[2][tid] + red2[3][tid];
    atomicAdd(&ws[WS_CCHAN + n * 64 + tid], t * (1.0f / CDIM));
  }
  int lane = tid & 63, w = tid >> 6;
  int k2base = __builtin_amdgcn_readfirstlane(w * 13);
  int nk2 = (w < 3) ? 13 : 10;
  float acc[13];
#pragma unroll
  for (int j = 0; j < 13; ++j) acc[j] = 0.0f;
#pragma unroll 2
  for (int cc = 0; cc < 128; ++cc) {
    float uv = u[cc * 53 + lane];
    const float* wrow = Wv + (c0 + cc) * NPIX;
#pragma unroll
    for (int j = 0; j < 13; ++j) {
      int k2 = k2base + j; if (k2 > 48) k2 = 48;
      acc[j] += uv * wrow[k2];
    }
  }
  if (lane < NPIX) {
    for (int j = 0; j < nk2; ++j)
      atomicAdd(&ws[WS_M + n * MSTRIDE_N + (k2base + j) * MSTRIDE_K2 + lane], acc[j]);
  }
}

// z_t, alpha_t (out), z_ext, beta (out)
__global__ __launch_bounds__(64) void k_zt(const float* __restrict__ Wh,
    float* __restrict__ ws, float* __restrict__ out) {
  __shared__ float gl[NPIX], whl[NPIX];
  int n = blockIdx.x, lane = threadIdx.x;
  if (lane < NPIX) {
    gl[lane] = ws[WS_HWG + n * 64 + lane];
    whl[lane] = Wh[lane];
  }
  __syncthreads();
  float z = 0.0f;
  if (lane < NPIX) {
    for (int k2 = 0; k2 < NPIX; ++k2) {
      float m = ws[WS_M + n * MSTRIDE_N + k2 * MSTRIDE_K2 + lane];
      z += tanh_f(tanh_f(m + gl[k2])) * whl[k2];
    }
  }
  float zm = (lane < NPIX) ? z : -1e30f;
  float m1 = zm;
  for (int off = 32; off; off >>= 1) m1 = fmaxf(m1, __shfl_xor(m1, off));
  float e = (lane < NPIX) ? __expf(z - m1) : 0.0f;
  float S1 = e;
  for (int off = 32; off; off >>= 1) S1 += __shfl_xor(S1, off);
  if (lane < NPIX) out[OUT_ALPHA + n * NPIX + lane] = e * rcp_fast(S1);
  float vz = (lane < NPIX) ? tanh_f(ws[WS_CS + n * 64 + lane]) * whl[lane] : 0.0f;
  for (int off = 32; off; off >>= 1) vz += __shfl_xor(vz, off);
  if (lane == 0) {
    float ze = vz;
    float m2 = fmaxf(m1, ze);
    float S2 = S1 * __expf(m1 - m2) + __expf(ze - m2);
    out[OUT_BETA + n] = __expf(ze - m2) * rcp_fast(S2);
  }
}

// c_spatial^T[d][n] = sum_k alpha_t[n][k] * V[b][k][d]
__global__ __launch_bounds__(256) void k_cspatial(const float* __restrict__ V,
    const float* __restrict__ out, float* __restrict__ ws) {
  __shared__ float al[NPIX];
  int tid = threadIdx.x, n = blockIdx.y, b = n >> 3;
  int d = blockIdx.x * 256 + tid;
  if (tid < NPIX) al[tid] = out[OUT_ALPHA + n * NPIX + tid];
  __syncthreads();
  float s = 0.0f;
#pragma unroll 7
  for (int k = 0; k < NPIX; ++k) s += al[k] * V[b * NPIX * CDIM + k * CDIM + d];
  ws[WS_CSPT + d * 64 + n] = s;
}

// chat^T[c][n] = s_gate*spat + c_gate*(cchan@Wchan) + h
__global__ __launch_bounds__(256) void k_chat(const float* __restrict__ hid,
    const float* __restrict__ Wchan, float* __restrict__ ws) {
  __shared__ float cl[NPIX];
  int tid = threadIdx.x, n = blockIdx.y;
  int c = blockIdx.x * 256 + tid;
  if (tid < NPIX) cl[tid] = ws[WS_CCHAN + n * 64 + tid];
  __syncthreads();
  float acc = 0.0f;
#pragma unroll 7
  for (int k = 0; k < NPIX; ++k) acc += cl[k] * Wchan[k * H + c];
  float chat = ws[WS_SG + n * H + c] * ws[WS_SPAT + n * H + c]
             + ws[WS_CG + n * H + c] * acc + hid[n * H + c];
  ws[WS_CHT + c * 64 + n] = chat;
}

extern "C" void kernel_launch(void* const* d_in, const int* in_sizes, int n_in,
                              void* d_out, int out_size, void* d_ws, size_t ws_size,
                              hipStream_t stream) {
  const float* x     = (const float*)d_in[0];
  const float* hid   = (const float*)d_in[1];
  const float* cells = (const float*)d_in[2];
  const float* V     = (const float*)d_in[3];
  const float* Wsx   = (const float*)d_in[4];
  const float* Wsh   = (const float*)d_in[5];
  const float* Wv    = (const float*)d_in[6];
  const float* Wg    = (const float*)d_in[7];
  const float* Ws_   = (const float*)d_in[8];
  const float* Wh    = (const float*)d_in[9];
  const float* Wfeat = (const float*)d_in[10];
  const float* Wcxt  = (const float*)d_in[11];
  const float* Wg2   = (const float*)d_in[12];
  const float* Wspat = (const float*)d_in[13];
  const float* Wchan = (const float*)d_in[14];
  const float* Wgvs  = (const float*)d_in[15];
  const float* Wgvc  = (const float*)d_in[16];
  const float* Wghs  = (const float*)d_in[17];
  const float* Wghc  = (const float*)d_in[18];
  const float* Wmlp  = (const float*)d_in[19];
  const float* bmlp  = (const float*)d_in[20];
  float* ws  = (float*)d_ws;
  float* out = (float*)d_out;

  hipLaunchKernelGGL(k_zero, dim3((ZERO_N + 255) / 256), dim3(256), 0, stream, ws, ZERO_N);
  hipLaunchKernelGGL(k_bias, dim3(40, 64), dim3(256), 0, stream, bmlp, out);
  hipLaunchKernelGGL(k_featmean, dim3(8, 8), dim3(256), 0, stream, V, ws);
  hipLaunchKernelGGL(k_tr, dim3(128, 3), dim3(256), 0, stream, x, hid, ws);
  hipLaunchKernelGGL(k_gemm_s, dim3(2, 32), dim3(256), 0, stream, Wsx, Wsh, ws);
  hipLaunchKernelGGL(k_act_s, dim3(128), dim3(256), 0, stream, cells, ws);
  hipLaunchKernelGGL(k_gemm_g2, dim3(2, 16), dim3(256), 0, stream, Wg2, ws);
  hipLaunchKernelGGL(k_cxt, dim3(8, 64), dim3(256), 0, stream, Wfeat, Wcxt, ws);
  hipLaunchKernelGGL(k_softmax0, dim3(64), dim3(256), 0, stream, ws);
  hipLaunchKernelGGL(k_cs_hwg, dim3(64), dim3(256), 0, stream, hid, Wg, Ws_, ws);
  hipLaunchKernelGGL(k_attnM, dim3(16, 64), dim3(256), 0, stream, V, Wv, ws);
  hipLaunchKernelGGL(k_zt, dim3(64), dim3(64), 0, stream, Wh, ws, out);
  hipLaunchKernelGGL(k_cspatial, dim3(8, 64), dim3(256), 0, stream, V, out, ws);
  hipLaunchKernelGGL(k_gemm_gates, dim3(2, 32, 2), dim3(256), 0, stream, Wgvs, Wghs, Wgvc, Wghc, ws);
  hipLaunchKernelGGL(k_act_g, dim3(128), dim3(256), 0, stream, ws);
  hipLaunchKernelGGL(k_gemm_spat, dim3(2, 64), dim3(256), 0, stream, Wspat, ws);
  hipLaunchKernelGGL(k_chat, dim3(2, 64), dim3(256), 0, stream, hid, Wchan, ws);
  hipLaunchKernelGGL(k_gemm_scores, dim3(40, 8), dim3(256), 0, stream, Wmlp, ws, out);
}